// Round 15
// baseline (174.625 us; speedup 1.0000x reference)
//
#include <hip/hip_runtime.h>
#include <hip/hip_bf16.h>

// Problem constants
#define NB   32      // batch
#define NC   24      // image channels
#define ND   12      // spatial
#define NN   144     // ND*ND objects
#define QD   11
#define GH   256
#define FOUT 10

typedef unsigned short u16;
typedef __attribute__((ext_vector_type(8))) short bf16x8;
typedef __attribute__((ext_vector_type(4))) float f32x4;
typedef __attribute__((ext_vector_type(16))) float f32x16;

// Workspace layout (u16 units unless noted):
//   Lqb  u16 [32][144][256]  off 0          (= L + q@Wg1_q + bg1, bf16)
//   Rb   u16 [32][144][256]  off 1179648
//   Bswz u16 [128][64][8]    off 2359296    (32x32x16 B-fragment order)
//   S    f32 [32][256]       byte-off 4849664
#define LQ_U16  0
#define R_U16   1179648
#define BS_U16  2359296
#define S_BYTE  4849664

__device__ inline float b2f(u16 v) {
  union { unsigned u; float f; } c; c.u = ((unsigned)v) << 16; return c.f;
}
__device__ inline u16 f2b(float f) {
  __hip_bfloat16 h = __float2bfloat16(f);
  return *reinterpret_cast<u16*>(&h);
}

// ---------------------------------------------------------------------------
// Fused prep:
//  blocks [0, 9216): per-object projections -> bf16 (Lq folds q-term + bg1).
//  blocks [9216, 9472): Wg2 -> bf16 B-fragment swizzle (32x32x16 frags):
//    frag f = ks*8 + nf; elem (l,e): k = ks*16 + (l>>5)*8 + e,
//    col = nf*32 + (l&31). Also zero S.
// ---------------------------------------------------------------------------
__global__ __launch_bounds__(256) void prep(const float* __restrict__ image,
                                            const float* __restrict__ question,
                                            const float* __restrict__ Wg1,
                                            const float* __restrict__ bg1,
                                            const float* __restrict__ Wg2,
                                            u16* __restrict__ Lq,
                                            u16* __restrict__ R,
                                            float* __restrict__ S,
                                            u16* __restrict__ Bswz) {
  int blk = blockIdx.x;
  int h   = threadIdx.x;
  if (blk < 2 * NB * NN) {
    int p     = blk % NN;
    int rest2 = blk / NN;
    int b     = rest2 & (NB - 1);
    int which = rest2 >> 5;
    const float* Wrow = Wg1 + which * (NC + 2) * GH;
    const float* img  = image + b * (NC * NN) + p;
    float acc = 0.f;
#pragma unroll
    for (int c = 0; c < NC; ++c) acc += img[c * NN] * Wrow[c * GH + h];
    int i = p / ND, j = p - i * ND;
    const float inv = 1.0f / (ND - 1);
    acc += (j * inv) * Wrow[24 * GH + h];
    acc += (i * inv) * Wrow[25 * GH + h];
    if (which == 0) {
      acc += bg1[h];
#pragma unroll
      for (int tq = 0; tq < QD; ++tq)
        acc += question[b * QD + tq] * Wg1[(2 * (NC + 2) + tq) * GH + h];
      Lq[(b * NN + p) * GH + h] = f2b(acc);
    } else {
      R[(b * NN + p) * GH + h] = f2b(acc);
    }
  } else {
    int tid = (blk - 2 * NB * NN) * 256 + h;   // 0..65535
    int e   = tid & 7;
    int l   = (tid >> 3) & 63;
    int f   = tid >> 9;                        // 0..127
    int ks  = f >> 3, nf = f & 7;
    int k = ks * 16 + ((l >> 5) << 3) + e;
    int n = (nf << 5) + (l & 31);
    Bswz[tid] = f2b(Wg2[k * GH + n]);
    if (tid < NB * GH) S[tid] = 0.f;
  }
}

// ---------------------------------------------------------------------------
// MFMA pair GEMM v15: v14 (32x32x16 + persistent-B) + T14 R-prefetch.
// Per tile: [build (consumes Rpre regs + L1-hot L) | bar | issue Rpre loads
// for t+1; mma 16 ks x 4 MFMA; epilogue | bar]. R's L2 traffic (64 KB/tile)
// now spreads across the 4.1k-cycle mma window instead of bursting at build
// (the measured 6k-cycle/tile stall). amdgpu_waves_per_eu(2,2) unlocks the
// 256-reg cap: bq 128 + Rpre 32 + af 8 + misc ~190 VGPR + 64 AGPR acc.
// Grid = 256 blocks (1/CU) XCD-pinned; ~20 tiles/block.
// ---------------------------------------------------------------------------
__global__ __launch_bounds__(512, 1)
__attribute__((amdgpu_waves_per_eu(2, 2)))
void pair_gemm(const u16* __restrict__ Lq,
               const u16* __restrict__ R,
               const u16* __restrict__ Bswz,
               const float* __restrict__ bg2,
               float* __restrict__ S) {
  const int bid = blockIdx.x;          // 0..255
  const int xcd = bid & 7;
  const int idx = bid >> 3;            // 0..31
  const int b   = xcd * 4 + (idx >> 3);
  const int bi  = idx & 7;             // 8 blocks per batch, 162 tiles
  const int t0  = bi * 20 + (bi < 2 ? bi : 2);
  const int cnt = 20 + (bi < 2 ? 1 : 0);

  // A fragments: [ks 16][mf 4][lane 64][8 bf16] = 64 KB
  __shared__ __align__(16) u16 As[16 * 4 * 64 * 8];

  const int t = threadIdx.x;
  const int w = t >> 6, l = t & 63;
  const int wn = w & 3, wm = w >> 2;
  // builder role: row brow (0..127), k-octet class oc (0..3)
  const int brow = t >> 2;
  const int oc   = t & 3;

  const u16* Lbase = Lq + b * NN * GH;
  const u16* Rbase = R + b * NN * GH;
  const u16* Bl    = Bswz + l * 8;

  // ---- persistent B: wave wn's 64 cols, all 16 k-steps (128 VGPRs) ----
  bf16x8 bq[2][16];
#pragma unroll
  for (int j = 0; j < 2; ++j)
#pragma unroll
    for (int ks = 0; ks < 16; ++ks)
      bq[j][ks] = *(const bf16x8*)
          (Bl + ((size_t)((ks << 3) | (wn << 1) | j) << 9));

  float bgv[2];
#pragma unroll
  for (int j = 0; j < 2; ++j)
    bgv[j] = bg2[(wn << 6) + (j << 5) + (l & 31)];
  float ssum[2] = {0.f, 0.f};

  // ---- R-prefetch state: this thread's R row for the CURRENT build tile ----
  int pj = (t0 * 128 + brow) % NN;
  bf16x8 Rpre[8];
  {
    const u16* Rr = Rbase + pj * GH;
#pragma unroll
    for (int u = 0; u < 8; ++u)
      Rpre[u] = *(const bf16x8*)(Rr + (oc + (u << 2)) * 8);
  }

  for (int tt = 0; tt < cnt; ++tt) {
    const bool hb = (tt + 1 < cnt);
    // ---- build phase: A-tile from Rpre regs + L (L1-hot, 1-2 rows) ----
    {
      int p = (t0 + tt) * 128 + brow;
      int i = p / NN;
      const u16* Lr = Lbase + i * GH;
#pragma unroll
      for (int u = 0; u < 8; ++u) {
        const int ko = oc + (u << 2);        // k-octet 0..31
        bf16x8 lv = *(const bf16x8*)(Lr + ko * 8);
        u16 o[8];
#pragma unroll
        for (int e = 0; e < 8; ++e) {
          float v = b2f((u16)lv[e]) + b2f((u16)Rpre[u][e]);
          o[e] = f2b(v > 0.f ? v : 0.f);
        }
        const int ks = ko >> 1;              // k-step 0..15
        const int kb = ko & 1;               // k-half within step
        const int mf = brow >> 5;            // 32-row frag 0..3
        const int pl = ((kb << 5) | (brow & 31)) ^ (oc << 1);  // swizzled lane
        *(bf16x8*)&As[((((ks << 2) | mf) << 6) | pl) << 3] = *(bf16x8*)o;
      }
    }
    __syncthreads();

    // ---- issue R prefetch for tile tt+1 (consumed after next barrier) ----
    if (hb) {
      pj = (pj >= 16) ? pj - 16 : pj + 128;  // j advances by 128 mod 144
      const u16* Rr = Rbase + pj * GH;
#pragma unroll
      for (int u = 0; u < 8; ++u)
        Rpre[u] = *(const bf16x8*)(Rr + (oc + (u << 2)) * 8);
    }

    // ---- MFMA phase: 16 ks x {2 ds_read A, 4 MFMA 32x32x16} ----
    f32x16 acc[2][2] = {};
#pragma unroll
    for (int ks = 0; ks < 16; ++ks) {
      bf16x8 af[2];
#pragma unroll
      for (int i = 0; i < 2; ++i) {
        const int mf = (wm << 1) | i;
        const int g  = ((((ks & 1) << 1) | (l >> 5)) << 1);
        af[i] = *(const bf16x8*)&As[((((ks << 2) | mf) << 6) | (l ^ g)) << 3];
      }
      __builtin_amdgcn_s_setprio(1);
#pragma unroll
      for (int i = 0; i < 2; ++i)
#pragma unroll
        for (int j = 0; j < 2; ++j)
          acc[i][j] = __builtin_amdgcn_mfma_f32_32x32x16_bf16(
              af[i], bq[j][ks], acc[i][j], 0, 0, 0);
      __builtin_amdgcn_s_setprio(0);
    }

    // epilogue: fold relu(acc + bg2) into running sums
#pragma unroll
    for (int j = 0; j < 2; ++j) {
      float s = 0.f;
#pragma unroll
      for (int i = 0; i < 2; ++i)
#pragma unroll
        for (int r = 0; r < 16; ++r) {
          float v = acc[i][j][r] + bgv[j];
          s += v > 0.f ? v : 0.f;
        }
      ssum[j] += s;
    }
    __syncthreads();
  }

  // Final reduce: 32x32 C/D col = l&31; lanes l, l+32 cover disjoint rows of
  // the same col -> one shfl; lanes 0..31 atomically add 2 cols each.
  float* Sb = S + b * GH;
#pragma unroll
  for (int j = 0; j < 2; ++j) {
    float s = ssum[j];
    s += __shfl_xor(s, 32, 64);
    if (l < 32) atomicAdd(&Sb[(wn << 6) + (j << 5) + l], s);
  }
}

// ---------------------------------------------------------------------------
// Final f-MLP: out = relu(S@Wf1+bf1)@Wf2+bf2. One block per batch.
// ---------------------------------------------------------------------------
__global__ __launch_bounds__(256) void final_mlp(const float* __restrict__ S,
                                                 const float* __restrict__ Wf1,
                                                 const float* __restrict__ bf1,
                                                 const float* __restrict__ Wf2,
                                                 const float* __restrict__ bf2,
                                                 float* __restrict__ out) {
  __shared__ float sS[GH];
  __shared__ float oS[GH];
  int b = blockIdx.x, h = threadIdx.x;
  sS[h] = S[b * GH + h];
  __syncthreads();
  float acc = bf1[h];
#pragma unroll 8
  for (int k = 0; k < GH; ++k) acc += sS[k] * Wf1[k * GH + h];
  oS[h] = acc > 0.f ? acc : 0.f;
  __syncthreads();
  if (h < FOUT) {
    float o = bf2[h];
#pragma unroll 8
    for (int k = 0; k < GH; ++k) o += oS[k] * Wf2[k * FOUT + h];
    out[b * FOUT + h] = o;
  }
}

extern "C" void kernel_launch(void* const* d_in, const int* in_sizes, int n_in,
                              void* d_out, int out_size, void* d_ws, size_t ws_size,
                              hipStream_t stream) {
  const float* image    = (const float*)d_in[0];
  const float* question = (const float*)d_in[1];
  const float* Wg1      = (const float*)d_in[2];
  const float* bg1      = (const float*)d_in[3];
  const float* Wg2      = (const float*)d_in[4];
  const float* bg2      = (const float*)d_in[5];
  const float* Wf1      = (const float*)d_in[6];
  const float* bf1      = (const float*)d_in[7];
  const float* Wf2      = (const float*)d_in[8];
  const float* bf2      = (const float*)d_in[9];
  float* out = (float*)d_out;

  u16*   wsb  = (u16*)d_ws;
  u16*   Lqp  = wsb + LQ_U16;
  u16*   Rp   = wsb + R_U16;
  u16*   Bswz = wsb + BS_U16;
  float* Sp   = (float*)((char*)d_ws + S_BYTE);

  prep<<<2 * NB * NN + 256, 256, 0, stream>>>(image, question, Wg1, bg1, Wg2,
                                              Lqp, Rp, Sp, Bswz);
  pair_gemm<<<256, 512, 0, stream>>>(Lqp, Rp, Bswz, bg2, Sp);
  final_mlp<<<NB, 256, 0, stream>>>(Sp, Wf1, bf1, Wf2, bf2, out);
}

// Round 16
// 137.460 us; speedup vs baseline: 1.2704x; 1.2704x over previous
//
#include <hip/hip_runtime.h>
#include <hip/hip_bf16.h>

// Problem constants
#define NB   32      // batch
#define NC   24      // image channels
#define ND   12      // spatial
#define NN   144     // ND*ND objects
#define QD   11
#define GH   256
#define FOUT 10

typedef unsigned short u16;
typedef __attribute__((ext_vector_type(8))) short bf16x8;
typedef __attribute__((ext_vector_type(4))) float f32x4;

// Workspace layout:
//   Lq  f32 [32][144][256]  float-off 0         (= L + q@Wg1_q + bg1 folded)
//   R   f32 [32][144][256]  float-off 1179648
//   S   f32 [32][256]       float-off 2359296
//   Bswz u16 [128][64][8]   u16-off  4734976    (16x16x32 B-fragment order)
#define LQ_OFF  0
#define R_OFF   1179648
#define S_OFF   2359296
#define BS_U16  4734976

__device__ inline u16 f2b(float f) {
  __hip_bfloat16 h = __float2bfloat16(f);
  return *reinterpret_cast<u16*>(&h);
}

// ---------------------------------------------------------------------------
// Fused prep (f32 Lq/R):
//  blocks [0, 9216): per-object projections (Lq folds q-term + bg1).
//  blocks [9216, 9472): Wg2 -> bf16 B-fragment swizzle; zero S.
// ---------------------------------------------------------------------------
__global__ __launch_bounds__(256) void prep(const float* __restrict__ image,
                                            const float* __restrict__ question,
                                            const float* __restrict__ Wg1,
                                            const float* __restrict__ bg1,
                                            const float* __restrict__ Wg2,
                                            float* __restrict__ Lq,
                                            float* __restrict__ R,
                                            float* __restrict__ S,
                                            u16* __restrict__ Bswz) {
  int blk = blockIdx.x;
  int h   = threadIdx.x;
  if (blk < 2 * NB * NN) {
    int p     = blk % NN;
    int rest2 = blk / NN;
    int b     = rest2 & (NB - 1);
    int which = rest2 >> 5;
    const float* Wrow = Wg1 + which * (NC + 2) * GH;
    const float* img  = image + b * (NC * NN) + p;
    float acc = 0.f;
#pragma unroll
    for (int c = 0; c < NC; ++c) acc += img[c * NN] * Wrow[c * GH + h];
    int i = p / ND, j = p - i * ND;
    const float inv = 1.0f / (ND - 1);
    acc += (j * inv) * Wrow[24 * GH + h];
    acc += (i * inv) * Wrow[25 * GH + h];
    if (which == 0) {
      acc += bg1[h];
#pragma unroll
      for (int tq = 0; tq < QD; ++tq)
        acc += question[b * QD + tq] * Wg1[(2 * (NC + 2) + tq) * GH + h];
      Lq[(b * NN + p) * GH + h] = acc;
    } else {
      R[(b * NN + p) * GH + h] = acc;
    }
  } else {
    int tid = (blk - 2 * NB * NN) * 256 + h;   // 0..65535
    int e   = tid & 7;
    int l   = (tid >> 3) & 63;
    int fid = tid >> 9;
    int kt  = fid >> 4, nt = fid & 15;
    int k = kt * 32 + ((l >> 4) << 3) + e;
    int n = (nt << 4) + (l & 15);
    Bswz[tid] = f2b(Wg2[k * GH + n]);
    if (tid < NB * GH) S[tid] = 0.f;
  }
}

// ---------------------------------------------------------------------------
// MFMA pair GEMM v16 = v12 structure + f32 packed build math.
// Block = 512 thr (8 waves, 2m x 4n), tile = 128 pairs x 256 cols.
// Phase-disjoint registers (v12-proven, 128-reg budget):
//   build: 16 transient f32x4 loads -> v_pk_add_f32 / v_pk_max_f32 /
//          compiler-fused v_cvt_pk_bf16_f32 (~12 VALU / 8 elems, was ~36)
//   mma:   acc 64 + af 16 + bfr 16 + misc ~ 116
// Single 64 KB LDS A-buffer; per tile [build | bar | mma + epi | bar].
// XOR-swizzled A store/read (v12, 0 conflicts). setprio around MFMA.
// Grid = 512 blocks (2/CU) XCD-pinned; ~10 tiles/block.
// ---------------------------------------------------------------------------
__global__ __launch_bounds__(512, 2) void pair_gemm(const float* __restrict__ Lq,
                                                    const float* __restrict__ R,
                                                    const u16* __restrict__ Bswz,
                                                    const float* __restrict__ bg2,
                                                    float* __restrict__ S) {
  const int bid = blockIdx.x;          // 0..511
  const int xcd = bid & 7;
  const int idx = bid >> 3;            // 0..63
  const int b   = xcd * 4 + (idx >> 4);
  const int bi  = idx & 15;            // 16 blocks per batch, 162 tiles
  const int t0  = bi * 10 + (bi < 2 ? bi : 2);
  const int cnt = 10 + (bi < 2 ? 1 : 0);

  // [kt 8][mf 8][lane 64][8 bf16] = 64 KB
  __shared__ __align__(16) u16 As[8 * 8 * 64 * 8];

  const int t = threadIdx.x;
  const int w = t >> 6, l = t & 63;
  const int wn = w & 3, wm = w >> 2;
  // builder role: row t>>2 (0..127), k-octet t&3
  const int brow = t >> 2;
  const int oc   = t & 3;
  const int mf_w   = brow >> 4;                              // 0..7
  const int lane_w = ((brow & 15) | (oc << 4)) ^ (oc << 1);  // 2-way (free)
  const int lane_r = l ^ (((l >> 4) & 3) << 1);

  const float* Lbase = Lq + b * NN * GH;
  const float* Rbase = R + b * NN * GH;
  const u16*   Bl    = Bswz + l * 8;

  float bgv[4];
#pragma unroll
  for (int nt = 0; nt < 4; ++nt)
    bgv[nt] = bg2[(wn << 6) + (nt << 4) + (l & 15)];
  float ssum[4] = {0.f, 0.f, 0.f, 0.f};

  for (int tt = 0; tt < cnt; ++tt) {
    // ---- build phase: whole 128x256 tile into LDS (packed f32 math) ----
    {
      int p = (t0 + tt) * 128 + brow;
      int i = p / NN, j = p - i * NN;
      const float* Lr = Lbase + i * GH + oc * 8;
      const float* Rr = Rbase + j * GH + oc * 8;
#pragma unroll
      for (int kt = 0; kt < 8; ++kt) {
        f32x4 s0 = *(const f32x4*)(Lr + kt * 32) + *(const f32x4*)(Rr + kt * 32);
        f32x4 s1 = *(const f32x4*)(Lr + kt * 32 + 4) +
                   *(const f32x4*)(Rr + kt * 32 + 4);
        s0 = __builtin_elementwise_max(s0, (f32x4)0.f);
        s1 = __builtin_elementwise_max(s1, (f32x4)0.f);
        u16 o[8];
#pragma unroll
        for (int e = 0; e < 4; ++e) { o[e] = f2b(s0[e]); o[e + 4] = f2b(s1[e]); }
        *(bf16x8*)&As[((((kt << 3) | mf_w) << 6) | lane_w) << 3] = *(bf16x8*)o;
      }
    }
    __syncthreads();

    // ---- MFMA phase ----
    f32x4 acc[4][4] = {};
#pragma unroll
    for (int kt = 0; kt < 8; ++kt) {
      bf16x8 af[4];
#pragma unroll
      for (int mf = 0; mf < 4; ++mf)
        af[mf] = *(const bf16x8*)
            &As[((((kt << 3) | (wm << 2) | mf) << 6) | lane_r) << 3];
      bf16x8 bfr[4];
#pragma unroll
      for (int nt = 0; nt < 4; ++nt) {
        int fid = (kt << 4) | (wn << 2) | nt;
        bfr[nt] = *(const bf16x8*)(Bl + ((size_t)fid << 9));
      }
      __builtin_amdgcn_s_setprio(1);
#pragma unroll
      for (int mf = 0; mf < 4; ++mf)
#pragma unroll
        for (int nt = 0; nt < 4; ++nt)
          acc[mf][nt] = __builtin_amdgcn_mfma_f32_16x16x32_bf16(
              af[mf], bfr[nt], acc[mf][nt], 0, 0, 0);
      __builtin_amdgcn_s_setprio(0);
    }
    // epilogue: fold relu(acc + bg2) into running sums
#pragma unroll
    for (int nt = 0; nt < 4; ++nt) {
      float s = 0.f;
#pragma unroll
      for (int mf = 0; mf < 4; ++mf)
#pragma unroll
        for (int r = 0; r < 4; ++r) {
          float v = acc[mf][nt][r] + bgv[nt];
          s += v > 0.f ? v : 0.f;
        }
      ssum[nt] += s;
    }
    __syncthreads();
  }

  // Final reduce: C/D col = l&15; shfl-reduce rows, one atomic per col slice
  float* Sb = S + b * GH;
#pragma unroll
  for (int nt = 0; nt < 4; ++nt) {
    float s = ssum[nt];
    s += __shfl_xor(s, 16, 64);
    s += __shfl_xor(s, 32, 64);
    if (l < 16) atomicAdd(&Sb[(wn << 6) + (nt << 4) + l], s);
  }
}

// ---------------------------------------------------------------------------
// Final f-MLP: out = relu(S@Wf1+bf1)@Wf2+bf2. One block per batch.
// ---------------------------------------------------------------------------
__global__ __launch_bounds__(256) void final_mlp(const float* __restrict__ S,
                                                 const float* __restrict__ Wf1,
                                                 const float* __restrict__ bf1,
                                                 const float* __restrict__ Wf2,
                                                 const float* __restrict__ bf2,
                                                 float* __restrict__ out) {
  __shared__ float sS[GH];
  __shared__ float oS[GH];
  int b = blockIdx.x, h = threadIdx.x;
  sS[h] = S[b * GH + h];
  __syncthreads();
  float acc = bf1[h];
#pragma unroll 8
  for (int k = 0; k < GH; ++k) acc += sS[k] * Wf1[k * GH + h];
  oS[h] = acc > 0.f ? acc : 0.f;
  __syncthreads();
  if (h < FOUT) {
    float o = bf2[h];
#pragma unroll 8
    for (int k = 0; k < GH; ++k) o += oS[k] * Wf2[k * FOUT + h];
    out[b * FOUT + h] = o;
  }
}

extern "C" void kernel_launch(void* const* d_in, const int* in_sizes, int n_in,
                              void* d_out, int out_size, void* d_ws, size_t ws_size,
                              hipStream_t stream) {
  const float* image    = (const float*)d_in[0];
  const float* question = (const float*)d_in[1];
  const float* Wg1      = (const float*)d_in[2];
  const float* bg1      = (const float*)d_in[3];
  const float* Wg2      = (const float*)d_in[4];
  const float* bg2      = (const float*)d_in[5];
  const float* Wf1      = (const float*)d_in[6];
  const float* bf1      = (const float*)d_in[7];
  const float* Wf2      = (const float*)d_in[8];
  const float* bf2      = (const float*)d_in[9];
  float* out = (float*)d_out;

  float* wsf  = (float*)d_ws;
  float* Lqp  = wsf + LQ_OFF;
  float* Rp   = wsf + R_OFF;
  float* Sp   = wsf + S_OFF;
  u16*   Bswz = (u16*)d_ws + BS_U16;

  prep<<<2 * NB * NN + 256, 256, 0, stream>>>(image, question, Wg1, bg1, Wg2,
                                              Lqp, Rp, Sp, Bswz);
  pair_gemm<<<512, 512, 0, stream>>>(Lqp, Rp, Bswz, bg2, Sp);
  final_mlp<<<NB, 256, 0, stream>>>(Sp, Wf1, bf1, Wf2, bf2, out);
}

// Round 17
// 110.643 us; speedup vs baseline: 1.5783x; 1.2424x over previous
//
#include <hip/hip_runtime.h>
#include <hip/hip_bf16.h>

// Problem constants
#define NB   32      // batch
#define NC   24      // image channels
#define ND   12      // spatial
#define NN   144     // ND*ND objects
#define QD   11
#define GH   256
#define FOUT 10

typedef unsigned short u16;
typedef __attribute__((ext_vector_type(8))) short bf16x8;
typedef __attribute__((ext_vector_type(4))) float f32x4;

// Workspace layout (u16 units unless noted):
//   Lqb  u16 [32][144][256]  off 0          (= L + q@Wg1_q + bg1, bf16)
//   Rb   u16 [32][144][256]  off 1179648
//   Bswz u16 [128][64][8]    off 2359296    (16x16x32 B-fragment order)
//   S    f32 [32][256]       byte-off 4849664
#define LQ_U16  0
#define R_U16   1179648
#define BS_U16  2359296
#define S_BYTE  4849664

__device__ inline float b2f(u16 v) {
  union { unsigned u; float f; } c; c.u = ((unsigned)v) << 16; return c.f;
}
__device__ inline u16 f2b(float f) {
  __hip_bfloat16 h = __float2bfloat16(f);
  return *reinterpret_cast<u16*>(&h);
}

// ---------------------------------------------------------------------------
// prep v2: Wg1 held in REGISTERS (26 + 11 floats/thread), image via scalar
// loads. blocks [0,256) = (which<<7)|(b<<2)|quarter, 36 objects each.
// blocks [256,512): Wg2 -> bf16 B-fragment swizzle; zero S.
// Cuts prep L2 traffic from ~276 MB (9216 Wg1 re-reads) to ~10 MB.
// ---------------------------------------------------------------------------
__global__ __launch_bounds__(256) void prep(const float* __restrict__ image,
                                            const float* __restrict__ question,
                                            const float* __restrict__ Wg1,
                                            const float* __restrict__ bg1,
                                            const float* __restrict__ Wg2,
                                            u16* __restrict__ Lq,
                                            u16* __restrict__ R,
                                            float* __restrict__ S,
                                            u16* __restrict__ Bswz) {
  int blk = blockIdx.x;
  int h   = threadIdx.x;
  if (blk < 256) {
    const int quarter = blk & 3;
    const int b       = (blk >> 2) & 31;
    const int which   = blk >> 7;
    // per-thread weight column (26 regs)
    float Wl[NC + 2];
#pragma unroll
    for (int r = 0; r < NC + 2; ++r)
      Wl[r] = Wg1[(which * (NC + 2) + r) * GH + h];
    // question-term + bias folded once (uniform over p), which==0 only
    float qacc = 0.f;
    if (which == 0) {
      qacc = bg1[h];
#pragma unroll
      for (int tq = 0; tq < QD; ++tq)
        qacc += question[b * QD + tq] * Wg1[(2 * (NC + 2) + tq) * GH + h];
    }
    const float* img = image + b * (NC * NN);
    u16* dst = (which == 0 ? Lq : R) + b * NN * GH + h;
    const float inv = 1.0f / (ND - 1);
#pragma unroll 4
    for (int p = quarter * 36; p < quarter * 36 + 36; ++p) {
      float acc = qacc;
#pragma unroll
      for (int c = 0; c < NC; ++c) acc += img[c * NN + p] * Wl[c];
      int i = p / ND, j = p - i * ND;
      acc += (j * inv) * Wl[24];
      acc += (i * inv) * Wl[25];
      dst[p * GH] = f2b(acc);
    }
  } else {
    int tid = (blk - 256) * 256 + h;   // 0..65535
    int e   = tid & 7;
    int l   = (tid >> 3) & 63;
    int fid = tid >> 9;
    int kt  = fid >> 4, nt = fid & 15;
    int k = kt * 32 + ((l >> 4) << 3) + e;
    int n = (nt << 4) + (l & 15);
    Bswz[tid] = f2b(Wg2[k * GH + n]);
    if (tid < NB * GH) S[tid] = 0.f;
  }
}

// ---------------------------------------------------------------------------
// MFMA pair GEMM v17 = v12 (proven 101 us) + anti-phase seeding.
// Block = 512 thr (8 waves, 2m x 4n), tile = 128 pairs x 256 cols, bf16 L/R.
// Phase-disjoint registers fit the 128-cap of (512,2) (v12-proven, clean).
// Per tile: [build | bar | mma + epi | bar]. 2 blocks/CU; co-resident pairs
// (bid>>3 differing by 32 under round-robin dispatch) are seeded into
// ANTI-phase by a one-time ~6k-cycle s_sleep: build VALU of one block then
// hides under the partner's MFMA phase (both modes are self-sustaining, so
// the seed should lock the good one). setprio(1) biases MFMA-phase waves.
// Grid = 512 blocks XCD-pinned; ~10 tiles/block.
// ---------------------------------------------------------------------------
__global__ __launch_bounds__(512, 2) void pair_gemm(const u16* __restrict__ Lq,
                                                    const u16* __restrict__ R,
                                                    const u16* __restrict__ Bswz,
                                                    const float* __restrict__ bg2,
                                                    float* __restrict__ S) {
  const int bid = blockIdx.x;          // 0..511
  const int xcd = bid & 7;
  const int idx = bid >> 3;            // 0..63
  const int b   = xcd * 4 + (idx >> 4);
  const int bi  = idx & 15;            // 16 blocks per batch, 162 tiles
  const int t0  = bi * 10 + (bi < 2 ? bi : 2);
  const int cnt = 10 + (bi < 2 ? 1 : 0);

  // one-time anti-phase seed for the second co-resident block on each CU
  if (idx & 32) __builtin_amdgcn_s_sleep(94);   // ~6k cycles

  // [kt 8][mf 8][lane 64][8 bf16] = 64 KB
  __shared__ __align__(16) u16 As[8 * 8 * 64 * 8];

  const int t = threadIdx.x;
  const int w = t >> 6, l = t & 63;
  const int wn = w & 3, wm = w >> 2;
  // builder role: row t>>2 (0..127), k-octet t&3
  const int brow = t >> 2;
  const int oc   = t & 3;
  const int mf_w   = brow >> 4;                              // 0..7
  const int lane_w = ((brow & 15) | (oc << 4)) ^ (oc << 1);  // 2-way (free)
  const int lane_r = l ^ (((l >> 4) & 3) << 1);

  const u16* Lbase = Lq + b * NN * GH;
  const u16* Rbase = R + b * NN * GH;
  const u16* Bl    = Bswz + l * 8;

  float bgv[4];
#pragma unroll
  for (int nt = 0; nt < 4; ++nt)
    bgv[nt] = bg2[(wn << 6) + (nt << 4) + (l & 15)];
  float ssum[4] = {0.f, 0.f, 0.f, 0.f};

  for (int tt = 0; tt < cnt; ++tt) {
    // ---- build phase: whole 128x256 tile into LDS (two 4-kt batches) ----
    {
      int p = (t0 + tt) * 128 + brow;
      int i = p / NN, j = p - i * NN;
      const u16* Lr = Lbase + i * GH + oc * 8;
      const u16* Rr = Rbase + j * GH + oc * 8;
#pragma unroll
      for (int half = 0; half < 2; ++half) {
        bf16x8 lv[4], rv[4];
#pragma unroll
        for (int q = 0; q < 4; ++q) {
          lv[q] = *(const bf16x8*)(Lr + ((half << 2) | q) * 32);
          rv[q] = *(const bf16x8*)(Rr + ((half << 2) | q) * 32);
        }
#pragma unroll
        for (int q = 0; q < 4; ++q) {
          const int kt = (half << 2) | q;
          u16 o[8];
#pragma unroll
          for (int e = 0; e < 8; ++e) {
            float v = b2f((u16)lv[q][e]) + b2f((u16)rv[q][e]);
            o[e] = f2b(v > 0.f ? v : 0.f);
          }
          *(bf16x8*)&As[((((kt << 3) | mf_w) << 6) | lane_w) << 3] =
              *(bf16x8*)o;
        }
      }
    }
    __syncthreads();

    // ---- MFMA phase ----
    f32x4 acc[4][4] = {};
#pragma unroll
    for (int kt = 0; kt < 8; ++kt) {
      bf16x8 af[4];
#pragma unroll
      for (int mf = 0; mf < 4; ++mf)
        af[mf] = *(const bf16x8*)
            &As[((((kt << 3) | (wm << 2) | mf) << 6) | lane_r) << 3];
      bf16x8 bfr[4];
#pragma unroll
      for (int nt = 0; nt < 4; ++nt) {
        int fid = (kt << 4) | (wn << 2) | nt;
        bfr[nt] = *(const bf16x8*)(Bl + ((size_t)fid << 9));
      }
      __builtin_amdgcn_s_setprio(1);
#pragma unroll
      for (int mf = 0; mf < 4; ++mf)
#pragma unroll
        for (int nt = 0; nt < 4; ++nt)
          acc[mf][nt] = __builtin_amdgcn_mfma_f32_16x16x32_bf16(
              af[mf], bfr[nt], acc[mf][nt], 0, 0, 0);
      __builtin_amdgcn_s_setprio(0);
    }
    // epilogue: fold relu(acc + bg2) into running sums
#pragma unroll
    for (int nt = 0; nt < 4; ++nt) {
      float s = 0.f;
#pragma unroll
      for (int mf = 0; mf < 4; ++mf)
#pragma unroll
        for (int r = 0; r < 4; ++r) {
          float v = acc[mf][nt][r] + bgv[nt];
          s += v > 0.f ? v : 0.f;
        }
      ssum[nt] += s;
    }
    __syncthreads();
  }

  // Final reduce: C/D col = l&15; shfl-reduce rows, one atomic per col slice
  float* Sb = S + b * GH;
#pragma unroll
  for (int nt = 0; nt < 4; ++nt) {
    float s = ssum[nt];
    s += __shfl_xor(s, 16, 64);
    s += __shfl_xor(s, 32, 64);
    if (l < 16) atomicAdd(&Sb[(wn << 6) + (nt << 4) + l], s);
  }
}

// ---------------------------------------------------------------------------
// Final f-MLP: out = relu(S@Wf1+bf1)@Wf2+bf2. One block per batch.
// ---------------------------------------------------------------------------
__global__ __launch_bounds__(256) void final_mlp(const float* __restrict__ S,
                                                 const float* __restrict__ Wf1,
                                                 const float* __restrict__ bf1,
                                                 const float* __restrict__ Wf2,
                                                 const float* __restrict__ bf2,
                                                 float* __restrict__ out) {
  __shared__ float sS[GH];
  __shared__ float oS[GH];
  int b = blockIdx.x, h = threadIdx.x;
  sS[h] = S[b * GH + h];
  __syncthreads();
  float acc = bf1[h];
#pragma unroll 8
  for (int k = 0; k < GH; ++k) acc += sS[k] * Wf1[k * GH + h];
  oS[h] = acc > 0.f ? acc : 0.f;
  __syncthreads();
  if (h < FOUT) {
    float o = bf2[h];
#pragma unroll 8
    for (int k = 0; k < GH; ++k) o += oS[k] * Wf2[k * FOUT + h];
    out[b * FOUT + h] = o;
  }
}

extern "C" void kernel_launch(void* const* d_in, const int* in_sizes, int n_in,
                              void* d_out, int out_size, void* d_ws, size_t ws_size,
                              hipStream_t stream) {
  const float* image    = (const float*)d_in[0];
  const float* question = (const float*)d_in[1];
  const float* Wg1      = (const float*)d_in[2];
  const float* bg1      = (const float*)d_in[3];
  const float* Wg2      = (const float*)d_in[4];
  const float* bg2      = (const float*)d_in[5];
  const float* Wf1      = (const float*)d_in[6];
  const float* bf1      = (const float*)d_in[7];
  const float* Wf2      = (const float*)d_in[8];
  const float* bf2      = (const float*)d_in[9];
  float* out = (float*)d_out;

  u16*   wsb  = (u16*)d_ws;
  u16*   Lqp  = wsb + LQ_U16;
  u16*   Rp   = wsb + R_U16;
  u16*   Bswz = wsb + BS_U16;
  float* Sp   = (float*)((char*)d_ws + S_BYTE);

  prep<<<512, 256, 0, stream>>>(image, question, Wg1, bg1, Wg2,
                                Lqp, Rp, Sp, Bswz);
  pair_gemm<<<512, 512, 0, stream>>>(Lqp, Rp, Bswz, bg2, Sp);
  final_mlp<<<NB, 256, 0, stream>>>(Sp, Wf1, bf1, Wf2, bf2, out);
}